// Round 2
// baseline (154.685 us; speedup 1.0000x reference)
//
#include <hip/hip_runtime.h>

typedef short bf16x8 __attribute__((ext_vector_type(8)));
typedef float f32x4 __attribute__((ext_vector_type(4)));

#define MFMA16(a, b, c) __builtin_amdgcn_mfma_f32_16x16x32_bf16(a, b, c, 0, 0, 0)

__device__ inline short f2bf(float f) {
  unsigned u = __builtin_bit_cast(unsigned, f);
  u += 0x7FFFu + ((u >> 16) & 1u);
  return (short)(u >> 16);
}
__device__ inline unsigned pack2(float lo, float hi) {
  return (unsigned)(unsigned short)f2bf(lo) | ((unsigned)(unsigned short)f2bf(hi) << 16);
}

// ---------------------------------------------------------------------------
// ws layout (bytes):
//   o_xmaj = 0        : 210x2048 bf16  (860160)
//   o_xmin = 860160   : 210x2048 bf16  (860160)
//   o_qs   = 1720320  : 256x1024 bf16  (524288)   Qs (pre-scaled by 1/32)
//   o_kw   = 2244608  : 320x1024 bf16  (655360)   rows 0..209=K, 210..274=wk, 275..287=0
//   o_vt   = 2899968  : 1024x256 bf16  (524288)   V transposed [n][m]
//   o_sp   = 3424256  : 224x288  f32   (258048)   S' = Qs @ [K;wk]^T
//   o_abf  = 3682304  : 256x256  bf16  (131072)   A padded (cols/rows >=210 zeroed)
//   o_av   = 3813376  : 256x1024 bf16  (524288)   A@V
// total 4337664 bytes
// ---------------------------------------------------------------------------

__global__ __launch_bounds__(256) void k_convert(const float* __restrict__ xmaj,
                                                 const float* __restrict__ xmin,
                                                 const float* __restrict__ wk,
                                                 short* __restrict__ xmaj_bf,
                                                 short* __restrict__ xmin_bf,
                                                 short* __restrict__ kw_bf) {
  int tid = blockIdx.x * 256 + threadIdx.x;
  int np = gridDim.x * 256;
  for (int i = tid; i < 210 * 2048; i += np) {
    xmaj_bf[i] = f2bf(xmaj[i]);
    xmin_bf[i] = f2bf(xmin[i]);
  }
  for (int i = tid; i < 65 * 1024; i += np) kw_bf[210 * 1024 + i] = f2bf(wk[i]);
  for (int i = tid; i < 13 * 1024; i += np) kw_bf[275 * 1024 + i] = 0;
}

// QKV: C[210x3072] = [Xmaj@Wq*scale | Xmin@Wk | Xmin@Wv], bf16 out.
// 192 blocks: 4 m-tiles x 48 n-tiles of 64x64, K=2048, BK=64.
// XCD swizzle: 4 m-tiles of one n-tile land on one XCD (weight tile L2 reuse).
__global__ __launch_bounds__(256) void k_qkv(const short* __restrict__ xmaj,
                                             const short* __restrict__ xmin,
                                             const float* __restrict__ Wq,
                                             const float* __restrict__ Wk,
                                             const float* __restrict__ Wv,
                                             short* __restrict__ qs,
                                             short* __restrict__ kw,
                                             short* __restrict__ vt) {
  __shared__ short As[64][72];
  __shared__ short Bs[64][72];
  int b = blockIdx.x;
  int x = b & 7, s = b >> 3;
  int ntile = x * 6 + (s >> 2);
  int mtile = s & 3;
  int nn0 = ntile * 64;
  int mat = nn0 >> 10;
  int ncol0 = nn0 & 1023;
  int m0 = mtile * 64;
  const short* A = (mat == 0) ? xmaj : xmin;
  const float* W = (mat == 0) ? Wq : (mat == 1 ? Wk : Wv);
  int t = threadIdx.x;
  int lane = t & 63, w = t >> 6;
  int wm = w >> 1, wn = w & 1;
  int l15 = lane & 15, l4 = lane >> 4;
  f32x4 acc[2][2] = {};
  int arow = t >> 3, ac8 = t & 7;
  int bkp = t >> 4, bc4 = t & 15;

  for (int k0 = 0; k0 < 2048; k0 += 64) {
    __syncthreads();
    // A stage: 64x64 bf16, 2 x 16B per thread
    *(uint4*)&As[arow][ac8 * 8] = *(const uint4*)(A + (m0 + arow) * 2048 + k0 + ac8 * 8);
    *(uint4*)&As[arow + 32][ac8 * 8] = *(const uint4*)(A + (m0 + arow + 32) * 2048 + k0 + ac8 * 8);
    // B stage with transpose: W[k][n] fp32 -> Bs[n][k] bf16, paired-k b32 writes
    for (int h = 0; h < 2; ++h) {
      int kp = bkp + h * 16;  // k-pair index 0..31
      const float* g0 = W + (size_t)(k0 + 2 * kp) * 1024 + ncol0 + bc4 * 4;
      float4 w0 = *(const float4*)g0;
      float4 w1 = *(const float4*)(g0 + 1024);
      int nl = bc4 * 4;
      *(unsigned*)&Bs[nl + 0][2 * kp] = pack2(w0.x, w1.x);
      *(unsigned*)&Bs[nl + 1][2 * kp] = pack2(w0.y, w1.y);
      *(unsigned*)&Bs[nl + 2][2 * kp] = pack2(w0.z, w1.z);
      *(unsigned*)&Bs[nl + 3][2 * kp] = pack2(w0.w, w1.w);
    }
    __syncthreads();
    for (int kk = 0; kk < 2; ++kk) {
      int ko = kk * 32 + l4 * 8;
      bf16x8 a0 = *(const bf16x8*)&As[wm * 32 + l15][ko];
      bf16x8 a1 = *(const bf16x8*)&As[wm * 32 + 16 + l15][ko];
      bf16x8 b0 = *(const bf16x8*)&Bs[wn * 32 + l15][ko];
      bf16x8 b1 = *(const bf16x8*)&Bs[wn * 32 + 16 + l15][ko];
      acc[0][0] = MFMA16(a0, b0, acc[0][0]);
      acc[0][1] = MFMA16(a0, b1, acc[0][1]);
      acc[1][0] = MFMA16(a1, b0, acc[1][0]);
      acc[1][1] = MFMA16(a1, b1, acc[1][1]);
    }
  }

  if (mat < 2) {
    float scale = (mat == 0) ? 0.03125f : 1.0f;
    short* dst = (mat == 0) ? qs : kw;
    for (int mi = 0; mi < 2; ++mi)
      for (int ni = 0; ni < 2; ++ni) {
        int r0 = m0 + wm * 32 + mi * 16 + l4 * 4;
        int c = ncol0 + wn * 32 + ni * 16 + l15;
        for (int j = 0; j < 4; ++j) {
          int r = r0 + j;
          if (r < 210) dst[r * 1024 + c] = f2bf(acc[mi][ni][j] * scale);
        }
      }
  } else {
    // V: transpose tile via LDS, store Vt[n][m] coalesced
    __syncthreads();
    for (int mi = 0; mi < 2; ++mi)
      for (int ni = 0; ni < 2; ++ni) {
        int nl = wn * 32 + ni * 16 + l15;
        int ml0 = wm * 32 + mi * 16 + l4 * 4;
        for (int j = 0; j < 4; ++j) As[nl][ml0 + j] = f2bf(acc[mi][ni][j]);
      }
    __syncthreads();
    for (int h = 0; h < 2; ++h) {
      int idx = t + h * 256;
      int nl = idx >> 3, c8 = idx & 7;
      int mg0 = m0 + c8 * 8;
      short* dstp = vt + (ncol0 + nl) * 256 + mg0;
      if (mg0 + 8 <= 210) {
        *(uint4*)dstp = *(const uint4*)&As[nl][c8 * 8];
      } else {
        for (int e = 0; e < 8; ++e)
          if (mg0 + e < 210) dstp[e] = As[nl][c8 * 8 + e];
      }
    }
  }
}

// S' = Qs @ [K;wk]^T : 224x288 fp32 out. Blocks 32x64, grid (5,7), K=1024.
__global__ __launch_bounds__(256) void k_sprime(const short* __restrict__ qs,
                                                const short* __restrict__ kwb,
                                                float* __restrict__ Sp) {
  __shared__ short As[32][72];
  __shared__ short Bs[64][72];
  int n0 = blockIdx.x * 64, m0 = blockIdx.y * 32;
  int t = threadIdx.x, lane = t & 63, w = t >> 6;
  int wm = w >> 1, wn = w & 1;
  int l15 = lane & 15, l4 = lane >> 4;
  f32x4 acc[2] = {};
  int arow = t >> 3, ac8 = t & 7;
  for (int k0 = 0; k0 < 1024; k0 += 64) {
    __syncthreads();
    if (arow < 32)
      *(uint4*)&As[arow][ac8 * 8] = *(const uint4*)(qs + (m0 + arow) * 1024 + k0 + ac8 * 8);
    *(uint4*)&Bs[arow][ac8 * 8] = *(const uint4*)(kwb + (n0 + arow) * 1024 + k0 + ac8 * 8);
    *(uint4*)&Bs[arow + 32][ac8 * 8] = *(const uint4*)(kwb + (n0 + arow + 32) * 1024 + k0 + ac8 * 8);
    __syncthreads();
    for (int kk = 0; kk < 2; ++kk) {
      int ko = kk * 32 + l4 * 8;
      bf16x8 a = *(const bf16x8*)&As[wm * 16 + l15][ko];
      bf16x8 b0 = *(const bf16x8*)&Bs[wn * 32 + l15][ko];
      bf16x8 b1 = *(const bf16x8*)&Bs[wn * 32 + 16 + l15][ko];
      acc[0] = MFMA16(a, b0, acc[0]);
      acc[1] = MFMA16(a, b1, acc[1]);
    }
  }
  for (int ni = 0; ni < 2; ++ni) {
    int r0 = m0 + wm * 16 + l4 * 4;
    int c = n0 + wn * 32 + ni * 16 + l15;
    if (c < 288)
      for (int j = 0; j < 4; ++j) Sp[(r0 + j) * 288 + c] = acc[ni][j];
  }
}

// softmax rows: logits[i][j] = Sp[i][j] + Sp[i][210+table[i][j]]
// Abf: bf16 A (padded to 256 cols/rows, zeros outside) for the AV MFMA.
// outA: fp32 A written straight to d_out (output 1).
__global__ __launch_bounds__(256) void k_softmax(const float* __restrict__ Sp,
                                                 const int* __restrict__ table,
                                                 short* __restrict__ Abf,
                                                 float* __restrict__ outA) {
  int i = blockIdx.x;
  int t = threadIdx.x;
  if (i >= 210) {
    Abf[i * 256 + t] = 0;
    return;
  }
  __shared__ float srow[288];
  __shared__ float red[4];
  for (int j = t; j < 288; j += 256) srow[j] = Sp[i * 288 + j];
  __syncthreads();
  float logit = -1e30f;
  if (t < 210) {
    int tb = table[i * 210 + t];
    logit = srow[t] + srow[210 + tb];
  }
  float m = logit;
  for (int o = 32; o; o >>= 1) m = fmaxf(m, __shfl_xor(m, o));
  if ((t & 63) == 0) red[t >> 6] = m;
  __syncthreads();
  m = fmaxf(fmaxf(red[0], red[1]), fmaxf(red[2], red[3]));
  float e = (t < 210) ? __expf(logit - m) : 0.0f;
  float s = e;
  for (int o = 32; o; o >>= 1) s += __shfl_xor(s, o);
  __syncthreads();
  if ((t & 63) == 0) red[t >> 6] = s;
  __syncthreads();
  s = red[0] + red[1] + red[2] + red[3];
  float a = e / s;
  Abf[i * 256 + t] = (t < 210) ? f2bf(a) : (short)0;
  if (t < 210) outA[i * 210 + t] = a;
}

// AV = A(224x256 pad, bf16) @ V : uses Vt[n][k]. Blocks 64x64, grid(16,4), K=256.
__global__ __launch_bounds__(256) void k_av(const short* __restrict__ Abf,
                                            const short* __restrict__ vt,
                                            short* __restrict__ av) {
  __shared__ short As[64][72];
  __shared__ short Bs[64][72];
  int n0 = blockIdx.x * 64, m0 = blockIdx.y * 64;
  int t = threadIdx.x, lane = t & 63, w = t >> 6;
  int wm = w >> 1, wn = w & 1;
  int l15 = lane & 15, l4 = lane >> 4;
  f32x4 acc[2][2] = {};
  int arow = t >> 3, ac8 = t & 7;
  for (int k0 = 0; k0 < 256; k0 += 64) {
    __syncthreads();
    *(uint4*)&As[arow][ac8 * 8] = *(const uint4*)(Abf + (m0 + arow) * 256 + k0 + ac8 * 8);
    *(uint4*)&As[arow + 32][ac8 * 8] = *(const uint4*)(Abf + (m0 + arow + 32) * 256 + k0 + ac8 * 8);
    *(uint4*)&Bs[arow][ac8 * 8] = *(const uint4*)(vt + (n0 + arow) * 256 + k0 + ac8 * 8);
    *(uint4*)&Bs[arow + 32][ac8 * 8] = *(const uint4*)(vt + (n0 + arow + 32) * 256 + k0 + ac8 * 8);
    __syncthreads();
    for (int kk = 0; kk < 2; ++kk) {
      int ko = kk * 32 + l4 * 8;
      bf16x8 a0 = *(const bf16x8*)&As[wm * 32 + l15][ko];
      bf16x8 a1 = *(const bf16x8*)&As[wm * 32 + 16 + l15][ko];
      bf16x8 b0 = *(const bf16x8*)&Bs[wn * 32 + l15][ko];
      bf16x8 b1 = *(const bf16x8*)&Bs[wn * 32 + 16 + l15][ko];
      acc[0][0] = MFMA16(a0, b0, acc[0][0]);
      acc[0][1] = MFMA16(a0, b1, acc[0][1]);
      acc[1][0] = MFMA16(a1, b0, acc[1][0]);
      acc[1][1] = MFMA16(a1, b1, acc[1][1]);
    }
  }
  for (int mi = 0; mi < 2; ++mi)
    for (int ni = 0; ni < 2; ++ni) {
      int r0 = m0 + wm * 32 + mi * 16 + l4 * 4;
      int c = n0 + wn * 32 + ni * 16 + l15;
      for (int j = 0; j < 4; ++j) {
        int r = r0 + j;
        if (r < 210) av[r * 1024 + c] = f2bf(acc[mi][ni][j]);
      }
    }
}

// Y = AV @ Wo : AV bf16 [m][k] k=1024, Wo fp32 transposed in staging. grid(16,4).
// Output fp32 (reference output dtype is float32).
__global__ __launch_bounds__(256) void k_y(const short* __restrict__ av,
                                           const float* __restrict__ Wo,
                                           float* __restrict__ outY) {
  __shared__ short As[64][72];
  __shared__ short Bs[64][72];
  int n0 = blockIdx.x * 64, m0 = blockIdx.y * 64;
  int t = threadIdx.x, lane = t & 63, w = t >> 6;
  int wm = w >> 1, wn = w & 1;
  int l15 = lane & 15, l4 = lane >> 4;
  f32x4 acc[2][2] = {};
  int arow = t >> 3, ac8 = t & 7;
  int bkp = t >> 4, bc4 = t & 15;
  for (int k0 = 0; k0 < 1024; k0 += 64) {
    __syncthreads();
    *(uint4*)&As[arow][ac8 * 8] = *(const uint4*)(av + (m0 + arow) * 1024 + k0 + ac8 * 8);
    *(uint4*)&As[arow + 32][ac8 * 8] = *(const uint4*)(av + (m0 + arow + 32) * 1024 + k0 + ac8 * 8);
    for (int h = 0; h < 2; ++h) {
      int kp = bkp + h * 16;
      const float* g0 = Wo + (size_t)(k0 + 2 * kp) * 1024 + n0 + bc4 * 4;
      float4 w0 = *(const float4*)g0;
      float4 w1 = *(const float4*)(g0 + 1024);
      int nl = bc4 * 4;
      *(unsigned*)&Bs[nl + 0][2 * kp] = pack2(w0.x, w1.x);
      *(unsigned*)&Bs[nl + 1][2 * kp] = pack2(w0.y, w1.y);
      *(unsigned*)&Bs[nl + 2][2 * kp] = pack2(w0.z, w1.z);
      *(unsigned*)&Bs[nl + 3][2 * kp] = pack2(w0.w, w1.w);
    }
    __syncthreads();
    for (int kk = 0; kk < 2; ++kk) {
      int ko = kk * 32 + l4 * 8;
      bf16x8 a0 = *(const bf16x8*)&As[wm * 32 + l15][ko];
      bf16x8 a1 = *(const bf16x8*)&As[wm * 32 + 16 + l15][ko];
      bf16x8 b0 = *(const bf16x8*)&Bs[wn * 32 + l15][ko];
      bf16x8 b1 = *(const bf16x8*)&Bs[wn * 32 + 16 + l15][ko];
      acc[0][0] = MFMA16(a0, b0, acc[0][0]);
      acc[0][1] = MFMA16(a0, b1, acc[0][1]);
      acc[1][0] = MFMA16(a1, b0, acc[1][0]);
      acc[1][1] = MFMA16(a1, b1, acc[1][1]);
    }
  }
  for (int mi = 0; mi < 2; ++mi)
    for (int ni = 0; ni < 2; ++ni) {
      int r0 = m0 + wm * 32 + mi * 16 + l4 * 4;
      int c = n0 + wn * 32 + ni * 16 + l15;
      for (int j = 0; j < 4; ++j) {
        int r = r0 + j;
        if (r < 210) outY[r * 1024 + c] = acc[mi][ni][j];
      }
    }
}

extern "C" void kernel_launch(void* const* d_in, const int* in_sizes, int n_in,
                              void* d_out, int out_size, void* d_ws, size_t ws_size,
                              hipStream_t stream) {
  const float* Xmaj = (const float*)d_in[0];
  const float* Xmin = (const float*)d_in[1];
  const float* Wq = (const float*)d_in[2];
  const float* Wk = (const float*)d_in[3];
  const float* Wv = (const float*)d_in[4];
  const float* Wo = (const float*)d_in[5];
  const float* wk = (const float*)d_in[6];
  const int* table = (const int*)d_in[7];

  char* ws = (char*)d_ws;
  short* xmaj_bf = (short*)(ws + 0);
  short* xmin_bf = (short*)(ws + 860160);
  short* qs = (short*)(ws + 1720320);
  short* kwb = (short*)(ws + 2244608);
  short* vt = (short*)(ws + 2899968);
  float* Sp = (float*)(ws + 3424256);
  short* Abf = (short*)(ws + 3682304);
  short* av = (short*)(ws + 3813376);

  float* outY = (float*)d_out;            // 210*1024 fp32
  float* outA = (float*)d_out + 215040;   // 210*210 fp32

  k_convert<<<512, 256, 0, stream>>>(Xmaj, Xmin, wk, xmaj_bf, xmin_bf, kwb);
  k_qkv<<<192, 256, 0, stream>>>(xmaj_bf, xmin_bf, Wq, Wk, Wv, qs, kwb, vt);
  k_sprime<<<dim3(5, 7), 256, 0, stream>>>(qs, kwb, Sp);
  k_softmax<<<256, 256, 0, stream>>>(Sp, table, Abf, outA);
  k_av<<<dim3(16, 4), 256, 0, stream>>>(Abf, vt, av);
  k_y<<<dim3(16, 4), 256, 0, stream>>>(av, Wo, outY);
}